// Round 14
// baseline (130.491 us; speedup 1.0000x reference)
//
#include <hip/hip_runtime.h>
#include <hip/hip_fp16.h>

#define NBINS 513
#define TFR   2048
#define NB    32
#define WIN   1024
#define HOP   256
#define PADT  384
#define OPB   524288
#define FR    16
#define TILES (TFR / FR)            /* 128 */
#define SPAN  (FR * HOP)            /* 4096 */
#define FSTRIDE 636                 /* half2 slots per frame row (pad phi) */
#define PHI(s) ((s) + 4*((s) >> 4)) /* slot map; 16-runs stay linear+16B aligned */
#define C45 0.70710678118654752f
#define TWOPI_1024 0.0061359231515425649f
#define TWOPI_512  0.0122718463030851306f
/* scale: 1/512 (IFFT) * 2/3 (interior envelope 1.5 pre-divided) */
#define SSC   (1.0f / 512.0f * 2.0f / 3.0f)
#define CDLT  0.99998117528260114f   /* cos(2*pi/1024) */
#define SDLT  0.00613588464915448f   /* sin(2*pi/1024) */

__device__ __forceinline__ float2 cadd(float2 a, float2 b){ return make_float2(a.x+b.x, a.y+b.y); }
__device__ __forceinline__ float2 csub(float2 a, float2 b){ return make_float2(a.x-b.x, a.y-b.y); }
__device__ __forceinline__ float2 cmul(float2 a, float2 b){ return make_float2(a.x*b.x - a.y*b.y, a.x*b.y + a.y*b.x); }
__device__ __forceinline__ float2 h2f(__half2 h){ return __half22float2(h); }
__device__ __forceinline__ __half2 f2h(float x, float y){ return __floats2half2_rn(x, y); }

__device__ __forceinline__ void wavesync() {
    __builtin_amdgcn_wave_barrier();
    asm volatile("" ::: "memory");
}

// e^{+i*pi*j/16}, j in [0,16] — literal quarter-wave cos table.
__device__ __forceinline__ float2 twid(int j) {
    const float C[17] = { 1.f, 0.98078528f, 0.92387953f, 0.83146961f, 0.70710678f,
                          0.55557023f, 0.38268343f, 0.19509032f, 0.f, -0.19509032f,
                         -0.38268343f, -0.55557023f, -0.70710678f, -0.83146961f,
                         -0.92387953f, -0.98078528f, -1.f };
    const int js = (j <= 8) ? (8 - j) : (j - 8);
    return make_float2(C[j], C[js]);   // (cos, sin) of +pi*j/16
}

// In-register N-pt inverse DFT (e^{+}), natural order in/out. N in {2,..,32}.
template<int N>
__device__ __forceinline__ void ifft_reg(float2* v) {
    if constexpr (N == 1) {
        (void)v;
    } else {
        float2 e[N/2], o[N/2];
        #pragma unroll
        for (int i = 0; i < N/2; ++i) { e[i] = v[2*i]; o[i] = v[2*i+1]; }
        ifft_reg<N/2>(e);
        ifft_reg<N/2>(o);
        #pragma unroll
        for (int q = 0; q < N/2; ++q) {
            const float2 w = twid(q * (32 / N));
            const float2 t = cmul(o[q], w);
            v[q]       = cadd(e[q], t);
            v[q + N/2] = csub(e[q], t);
        }
    }
}

// hann(2n), hann(2n+1) from (c,s) = (cos,sin)(2*pi*n/1024)
__device__ __forceinline__ float2 hann_cs(float c, float s)
{
    const float w0 = 1.0f - c*c;
    const float c2 = 2.0f*c*c - 1.0f;
    const float s2 = 2.0f*c*s;
    const float w1 = 0.5f - 0.5f*(c2*CDLT - s2*SDLT);
    return make_float2(w0, w1);
}

__global__ __launch_bounds__(256) void zero_seams(float* __restrict__ out)
{
    const int total = NB * (TILES + 1) * 768;
    for (int id = blockIdx.x * 256 + threadIdx.x; id < total; id += gridDim.x * 256) {
        const int q = id % 768;
        const int r = id / 768;
        const int s = r % (TILES + 1);
        const int bb = r / (TILES + 1);
        const int p  = s * SPAN + q;
        const int oi = p - PADT;
        if ((unsigned)oi < (unsigned)OPB) out[(size_t)bb * OPB + oi] = 0.f;
    }
}

// One block = 16 frames. Reg staging + trick -> f16 Z in LDS ->
// stage1: radix-32 in-reg (1 bfly/lane) -> stage2: radix-16 in-reg
// (2 bflys/lane, contiguous b128 LDS) -> register OLA -> direct stores.
__global__ __launch_bounds__(256, 4) void istft16(
    const float* __restrict__ sr, const float* __restrict__ si,
    float* __restrict__ out)
{
    __shared__ __align__(16) __half2 stile[FR * FSTRIDE];  // 40704 B, 4 blk/CU

    const int tid = threadIdx.x;
    const int bid = blockIdx.x;
    const int nwg = NB * TILES;                           // 4096
    const int swz = (bid & 7) * (nwg >> 3) + (bid >> 3);  // XCD-chunked
    const int b    = swz / TILES;
    const int tile = swz % TILES;
    const int j0   = tile * FR;

    // ---- staging loads first ----
    const size_t gbase = (size_t)b * NBINS * TFR + (size_t)j0;
    const size_t gaA = gbase + (size_t)tid * TFR;
    const size_t gaB = gbase + (size_t)(512 - tid) * TFR;
    float4 rA0 = *(const float4*)(sr + gaA);
    float4 rA1 = *(const float4*)(sr + gaA + 4);
    float4 rA2 = *(const float4*)(sr + gaA + 8);
    float4 rA3 = *(const float4*)(sr + gaA + 12);
    float4 iA0 = *(const float4*)(si + gaA);
    float4 iA1 = *(const float4*)(si + gaA + 4);
    float4 iA2 = *(const float4*)(si + gaA + 8);
    float4 iA3 = *(const float4*)(si + gaA + 12);
    float4 rB0 = *(const float4*)(sr + gaB);
    float4 rB1 = *(const float4*)(sr + gaB + 4);
    float4 rB2 = *(const float4*)(sr + gaB + 8);
    float4 rB3 = *(const float4*)(sr + gaB + 12);
    float4 iB0 = *(const float4*)(si + gaB);
    float4 iB1 = *(const float4*)(si + gaB + 4);
    float4 iB2 = *(const float4*)(si + gaB + 8);
    float4 iB3 = *(const float4*)(si + gaB + 12);

    float2 rc, ic;
    if (tid < 8) {                      // bin-256 rows, 2 frames each
        const size_t gaC = gbase + (size_t)256 * TFR + 2*tid;
        rc = *(const float2*)(sr + gaC);
        ic = *(const float2*)(si + gaC);
    }
    if (tid == 0) {                     // irfft ignores Im of bins 0 and 512
        const float4 z4 = make_float4(0.f,0.f,0.f,0.f);
        iA0=iA1=iA2=iA3=z4; iB0=iB1=iB2=iB3=z4;
    }

    // ---- half-size trick in registers (per-thread sincos twiddle) ----
    float swt, cwt;
    sincosf(TWOPI_1024 * (float)tid, &swt, &cwt);
    {
        const float h = 0.5f * SSC;
        const int pk  = PHI(tid);
        const int pk2 = PHI(512 - tid);
        const bool wr2 = (tid != 0);    // k=0 has no (512-k) partner slot
#define TRICK(F, XKX, XKY, XMX, XMY) do {                                   \
            const float Ex = h*((XKX)+(XMX)), Ey = h*((XKY)-(XMY));         \
            const float Dx = h*((XKX)-(XMX)), Dy = h*((XKY)+(XMY));         \
            const float Ox = Dx*cwt - Dy*swt, Oy = Dx*swt + Dy*cwt;         \
            stile[(F)*FSTRIDE + pk] = f2h(Ex - Oy, Ey + Ox);                \
            if (wr2) stile[(F)*FSTRIDE + pk2] = f2h(Ex + Oy, Ox - Ey);      \
        } while (0)
        TRICK(0,  rA0.x, iA0.x, rB0.x, iB0.x);
        TRICK(1,  rA0.y, iA0.y, rB0.y, iB0.y);
        TRICK(2,  rA0.z, iA0.z, rB0.z, iB0.z);
        TRICK(3,  rA0.w, iA0.w, rB0.w, iB0.w);
        TRICK(4,  rA1.x, iA1.x, rB1.x, iB1.x);
        TRICK(5,  rA1.y, iA1.y, rB1.y, iB1.y);
        TRICK(6,  rA1.z, iA1.z, rB1.z, iB1.z);
        TRICK(7,  rA1.w, iA1.w, rB1.w, iB1.w);
        TRICK(8,  rA2.x, iA2.x, rB2.x, iB2.x);
        TRICK(9,  rA2.y, iA2.y, rB2.y, iB2.y);
        TRICK(10, rA2.z, iA2.z, rB2.z, iB2.z);
        TRICK(11, rA2.w, iA2.w, rB2.w, iB2.w);
        TRICK(12, rA3.x, iA3.x, rB3.x, iB3.x);
        TRICK(13, rA3.y, iA3.y, rB3.y, iB3.y);
        TRICK(14, rA3.z, iA3.z, rB3.z, iB3.z);
        TRICK(15, rA3.w, iA3.w, rB3.w, iB3.w);
#undef TRICK
        if (tid < 8) {                  // Z[256] = conj(X[256]) * SSC
            stile[(2*tid)  *FSTRIDE + PHI(256)] = f2h(rc.x * SSC, -ic.x * SSC);
            stile[(2*tid+1)*FSTRIDE + PHI(256)] = f2h(rc.y * SSC, -ic.y * SSC);
        }
    }
    __syncthreads();                                   // B1 (cross-wave)

    // ---- 512-pt IFFT: radix-32 then radix-16, lane map f=l&3, i0=l>>2 ----
    {
        const int lw = tid & 63, w = tid >> 6;
        const int fr = (w << 2) | (lw & 3);            // frame 0..15
        const int i0 = lw >> 2;                        // bfly index 0..15
        __half2* row = &stile[fr * FSTRIDE];

        // stage 1: y_{k,q} = IDFT32_p(Z[k+16p]); *= W512^{kq}; slot phi(k+16q)=20q+k
        {
            float2 v[32];
            #pragma unroll
            for (int p = 0; p < 32; ++p) v[p] = h2f(row[20*p + i0]);
            ifft_reg<32>(v);
            float sw1, cw1;
            sincosf(TWOPI_512 * (float)i0, &sw1, &cw1);
            const float2 w1 = make_float2(cw1, sw1);
            float2 wacc = w1;
            #pragma unroll
            for (int q = 1; q < 32; ++q) {
                v[q] = cmul(v[q], wacc);
                wacc = cmul(wacc, w1);
            }
            #pragma unroll
            for (int q = 0; q < 32; ++q) row[20*q + i0] = f2h(v[q].x, v[q].y);
        }
        wavesync();                                    // intra-wave dep only

        // stage 2: X[q'+32m] = IDFT16_k(slot 20q'+k); store at slot 20q'+m
        #pragma unroll
        for (int hh = 0; hh < 2; ++hh) {
            const int qp = i0 + 16*hh;
            float2 z[16];
            #pragma unroll
            for (int c = 0; c < 4; ++c) {
                const float4 raw = *(const float4*)&row[20*qp + 4*c];
                const __half2* hp = (const __half2*)&raw;
                z[4*c+0] = h2f(hp[0]); z[4*c+1] = h2f(hp[1]);
                z[4*c+2] = h2f(hp[2]); z[4*c+3] = h2f(hp[3]);
            }
            ifft_reg<16>(z);
            #pragma unroll
            for (int c = 0; c < 4; ++c) {
                float4 raw;
                __half2* hp = (__half2*)&raw;
                hp[0] = f2h(z[4*c+0].x, z[4*c+0].y);
                hp[1] = f2h(z[4*c+1].x, z[4*c+1].y);
                hp[2] = f2h(z[4*c+2].x, z[4*c+2].y);
                hp[3] = f2h(z[4*c+3].x, z[4*c+3].y);
                *(float4*)&row[20*qp + 4*c] = raw;
            }
        }
    }
    __syncthreads();                                   // B4 (cross-wave: OLA)

    // ---- OLA weights from (cwt,swt) via exact rotations (R12-verified) ----
    const bool tlo = (tid < 128);       // wave-coherent
    const float c4 = (cwt - swt) * C45, s4 = (cwt + swt) * C45;   // +pi/4
    const float cm = (cwt + swt) * C45, sm = (swt - cwt) * C45;   // -pi/4
    const float2 wE0 = hann_cs(cwt, swt);
    const float2 wE1 = hann_cs(-swt, cwt);
    const float2 wO0 = tlo ? hann_cs(c4, s4)  : hann_cs(cm, sm);
    const float2 wO1 = tlo ? hann_cs(-cm, c4) : hann_cs(c4, s4);

    // sample n lives at slot 20*(n&31) + (n>>5)
    const int jsE0 = 20*(tid & 31) + (tid >> 5);
    const int jsE1 = jsE0 + 8;
    const int jsO0 = 20*(tid & 31) + ((tid >> 5) ^ 4);
    const int jsO1 = jsO0 + 8;

    float2 a0 = make_float2(0.f,0.f), a1=a0, a2=a0, a3=a0, a4=a0,
           a5 = a0, a6=a0, a7=a0, a8=a0, a9=a0;

#define OLA_STEP(F, JS, ACCV, W) do {                                       \
        const float2 z_ = h2f(stile[(F)*FSTRIDE + (JS)]);                   \
        ACCV.x += z_.x * W.x;                                               \
        ACCV.y += z_.y * W.y;                                               \
    } while (0)

    OLA_STEP(0,jsE0,a0,wE0);  OLA_STEP(0,jsE1,a1,wE1);
    if (tlo) { OLA_STEP(1,jsO0,a1,wO0);  OLA_STEP(1,jsO1,a2,wO1); }
    else     { OLA_STEP(1,jsO0,a0,wO0);  OLA_STEP(1,jsO1,a1,wO1); }
    OLA_STEP(2,jsE0,a1,wE0);  OLA_STEP(2,jsE1,a2,wE1);
    if (tlo) { OLA_STEP(3,jsO0,a2,wO0);  OLA_STEP(3,jsO1,a3,wO1); }
    else     { OLA_STEP(3,jsO0,a1,wO0);  OLA_STEP(3,jsO1,a2,wO1); }
    OLA_STEP(4,jsE0,a2,wE0);  OLA_STEP(4,jsE1,a3,wE1);
    if (tlo) { OLA_STEP(5,jsO0,a3,wO0);  OLA_STEP(5,jsO1,a4,wO1); }
    else     { OLA_STEP(5,jsO0,a2,wO0);  OLA_STEP(5,jsO1,a3,wO1); }
    OLA_STEP(6,jsE0,a3,wE0);  OLA_STEP(6,jsE1,a4,wE1);
    if (tlo) { OLA_STEP(7,jsO0,a4,wO0);  OLA_STEP(7,jsO1,a5,wO1); }
    else     { OLA_STEP(7,jsO0,a3,wO0);  OLA_STEP(7,jsO1,a4,wO1); }
    OLA_STEP(8,jsE0,a4,wE0);  OLA_STEP(8,jsE1,a5,wE1);
    if (tlo) { OLA_STEP(9,jsO0,a5,wO0);  OLA_STEP(9,jsO1,a6,wO1); }
    else     { OLA_STEP(9,jsO0,a4,wO0);  OLA_STEP(9,jsO1,a5,wO1); }
    OLA_STEP(10,jsE0,a5,wE0); OLA_STEP(10,jsE1,a6,wE1);
    if (tlo) { OLA_STEP(11,jsO0,a6,wO0); OLA_STEP(11,jsO1,a7,wO1); }
    else     { OLA_STEP(11,jsO0,a5,wO0); OLA_STEP(11,jsO1,a6,wO1); }
    OLA_STEP(12,jsE0,a6,wE0); OLA_STEP(12,jsE1,a7,wE1);
    if (tlo) { OLA_STEP(13,jsO0,a7,wO0); OLA_STEP(13,jsO1,a8,wO1); }
    else     { OLA_STEP(13,jsO0,a6,wO0); OLA_STEP(13,jsO1,a7,wO1); }
    OLA_STEP(14,jsE0,a7,wE0); OLA_STEP(14,jsE1,a8,wE1);
    if (tlo) { OLA_STEP(15,jsO0,a8,wO0); OLA_STEP(15,jsO1,a9,wO1); }
    else     { OLA_STEP(15,jsO0,a7,wO0); OLA_STEP(15,jsO1,a8,wO1); }
#undef OLA_STEP

    // ---- direct stores (values already env-divided by 1.5) ----
    const size_t ob = (size_t)b * OPB;
    const int pb = tile * SPAN;
#define STORE_SEAM(A, G) do {                                               \
        const int oi_ = pb + 2*(tid + 256*(G)) - PADT;                      \
        if ((unsigned)oi_ < (unsigned)OPB)       atomicAdd(&out[ob + oi_],     A.x); \
        if ((unsigned)(oi_+1) < (unsigned)OPB)   atomicAdd(&out[ob + oi_ + 1], A.y); \
    } while (0)
#define STORE_PLAIN(A, G) do {                                              \
        const int oi_ = pb + 2*(tid + 256*(G)) - PADT;                      \
        *(float2*)(out + ob + oi_) = A;                                     \
    } while (0)

    STORE_SEAM(a0, 0);                   // idx [0,512): head seam
    if (tlo) STORE_SEAM(a1, 1);          // [512,768): head seam
    else     STORE_PLAIN(a1, 1);         // [768,1024): interior
    STORE_PLAIN(a2, 2);
    STORE_PLAIN(a3, 3);
    STORE_PLAIN(a4, 4);
    STORE_PLAIN(a5, 5);
    STORE_PLAIN(a6, 6);
    STORE_PLAIN(a7, 7);                  // up to idx 4096
    STORE_SEAM(a8, 8);                   // [4096,4608): tail seam
    if (tlo) STORE_SEAM(a9, 9);          // [4608,4864): tail seam
#undef STORE_SEAM
#undef STORE_PLAIN
}

// env != 1.5 only within 384 samples of the global edges; rescale those.
__global__ __launch_bounds__(256) void edge_fix(float* __restrict__ out)
{
    const int id = blockIdx.x * 256 + threadIdx.x;   // 768 * NB total
    if (id >= 768 * NB) return;
    const int bb = id / 768;
    const int r  = id % 768;
    const int oi = (r < 384) ? r : (OPB - 768 + r);
    const int p  = oi + PADT;
    int jlo = (p - 768) >> 8; if (jlo < 0) jlo = 0;
    int jhi = p >> 8;         if (jhi > TFR - 1) jhi = TFR - 1;
    float e = 0.f;
    for (int j = jlo; j <= jhi; ++j) {
        const float wv = 0.5f - 0.5f * cosf(TWOPI_1024 * (float)(p - j * HOP));
        e += wv * wv;
    }
    out[(size_t)bb * OPB + oi] *= 1.5f / e;
}

extern "C" void kernel_launch(void* const* d_in, const int* in_sizes, int n_in,
                              void* d_out, int out_size, void* d_ws, size_t ws_size,
                              hipStream_t stream) {
    const float* sr = (const float*)d_in[0];
    const float* si = (const float*)d_in[1];
    float* out = (float*)d_out;

    hipLaunchKernelGGL(zero_seams, dim3(2048), dim3(256), 0, stream, out);
    hipLaunchKernelGGL(istft16, dim3(NB * TILES), dim3(256), 0, stream, sr, si, out);
    hipLaunchKernelGGL(edge_fix, dim3((768 * NB + 255) / 256), dim3(256), 0, stream, out);
}

// Round 15
// 111.602 us; speedup vs baseline: 1.1693x; 1.1693x over previous
//
#include <hip/hip_runtime.h>
#include <hip/hip_fp16.h>

#define NBINS 513
#define TFR   2048
#define NB    32
#define WIN   1024
#define HOP   256
#define PADT  384
#define OPB   524288
#define FR    16
#define TILES (TFR / FR)            /* 128 */
#define SPAN  (FR * HOP)            /* 4096 */
#define FSTRIDE 545                 /* half2 per frame row, padded */
#define PIDX(i) ((i) + ((i) >> 4))
#define C45 0.70710678118654752f
#define TWOPI_1024 0.0061359231515425649f
/* scale: 1/512 (IFFT) * 2/3 (interior envelope 1.5 pre-divided) */
#define SSC   (1.0f / 512.0f * 2.0f / 3.0f)
#define CDLT  0.99998117528260114f   /* cos(2*pi/1024) */
#define SDLT  0.00613588464915448f   /* sin(2*pi/1024) */

__device__ __forceinline__ float2 cadd(float2 a, float2 b){ return make_float2(a.x+b.x, a.y+b.y); }
__device__ __forceinline__ float2 csub(float2 a, float2 b){ return make_float2(a.x-b.x, a.y-b.y); }
__device__ __forceinline__ float2 cmul(float2 a, float2 b){ return make_float2(a.x*b.x - a.y*b.y, a.x*b.y + a.y*b.x); }
__device__ __forceinline__ float2 h2f(__half2 h){ return __half22float2(h); }
__device__ __forceinline__ __half2 f2h(float x, float y){ return __floats2half2_rn(x, y); }

#define BFLY8(u0,u1,u2,u3,u4,u5,u6,u7, v0,v1,v2,v3,v4,v5,v6,v7)            \
    float2 s0=cadd(u0,u4), t0=csub(u0,u4);                                  \
    float2 s1=cadd(u1,u5), t1=csub(u1,u5);                                  \
    float2 s2=cadd(u2,u6), t2=csub(u2,u6);                                  \
    float2 s3=cadd(u3,u7), t3=csub(u3,u7);                                  \
    t1 = make_float2(C45*(t1.x - t1.y),  C45*(t1.x + t1.y));                \
    t2 = make_float2(-t2.y, t2.x);                                          \
    t3 = make_float2(-C45*(t3.x + t3.y), C45*(t3.x - t3.y));                \
    float2 p0=cadd(s0,s2), p2=csub(s0,s2);                                  \
    float2 p1=cadd(s1,s3), p3=csub(s1,s3); p3 = make_float2(-p3.y, p3.x);   \
    float2 q0=cadd(t0,t2), q2=csub(t0,t2);                                  \
    float2 q1=cadd(t1,t3), q3=csub(t1,t3); q3 = make_float2(-q3.y, q3.x);   \
    float2 v0=cadd(p0,p1), v4=csub(p0,p1);                                  \
    float2 v2=cadd(p2,p3), v6=csub(p2,p3);                                  \
    float2 v1=cadd(q0,q1), v5=csub(q0,q1);                                  \
    float2 v3=cadd(q2,q3), v7=csub(q2,q3);

// In-place radix-8 DIF stage on f16 LDS, i in [0,64). L=64,8,1.
template<int L>
__device__ __forceinline__ void fft_stage(__half2* __restrict__ row,
                                          const float2* __restrict__ ph, int i)
{
    const int k    = i & (L - 1);
    const int base = ((i & ~(L - 1)) << 3) + k;
    float2 u0 = h2f(row[PIDX(base + 0*L)]);
    float2 u1 = h2f(row[PIDX(base + 1*L)]);
    float2 u2 = h2f(row[PIDX(base + 2*L)]);
    float2 u3 = h2f(row[PIDX(base + 3*L)]);
    float2 u4 = h2f(row[PIDX(base + 4*L)]);
    float2 u5 = h2f(row[PIDX(base + 5*L)]);
    float2 u6 = h2f(row[PIDX(base + 6*L)]);
    float2 u7 = h2f(row[PIDX(base + 7*L)]);
    BFLY8(u0,u1,u2,u3,u4,u5,u6,u7, v0,v1,v2,v3,v4,v5,v6,v7)
    if constexpr (L > 1) {
        const float2 w1 = ph[k * (128 / L)];   // idx <= 126
        float2 wq = w1;
        v1 = cmul(v1, wq);
        wq = cmul(wq, w1); v2 = cmul(v2, wq);
        wq = cmul(wq, w1); v3 = cmul(v3, wq);
        wq = cmul(wq, w1); v4 = cmul(v4, wq);
        wq = cmul(wq, w1); v5 = cmul(v5, wq);
        wq = cmul(wq, w1); v6 = cmul(v6, wq);
        wq = cmul(wq, w1); v7 = cmul(v7, wq);
    }
    row[PIDX(base + 0*L)] = f2h(v0.x, v0.y);
    row[PIDX(base + 1*L)] = f2h(v1.x, v1.y);
    row[PIDX(base + 2*L)] = f2h(v2.x, v2.y);
    row[PIDX(base + 3*L)] = f2h(v3.x, v3.y);
    row[PIDX(base + 4*L)] = f2h(v4.x, v4.y);
    row[PIDX(base + 5*L)] = f2h(v5.x, v5.y);
    row[PIDX(base + 6*L)] = f2h(v6.x, v6.y);
    row[PIDX(base + 7*L)] = f2h(v7.x, v7.y);
}

// (hann(2n), hann(2n+1)) for n in [0,512), from the 257-entry quarter table.
__device__ __forceinline__ float2 hann_pair(const float2* __restrict__ ph, int n)
{
    const bool mir = n > 256;
    const int  m   = mir ? 512 - n : n;
    const float2 cs = ph[m];
    const float c = mir ? -cs.x : cs.x;
    const float s = cs.y;
    const float w0 = 1.0f - c*c;
    const float c2 = 2.0f*c*c - 1.0f;
    const float s2 = 2.0f*c*s;
    const float w1 = 0.5f - 0.5f*(c2*CDLT - s2*SDLT);
    return make_float2(w0, w1);
}

__global__ __launch_bounds__(256) void zero_seams(float* __restrict__ out)
{
    const int total = NB * (TILES + 1) * 768;
    for (int id = blockIdx.x * 256 + threadIdx.x; id < total; id += gridDim.x * 256) {
        const int q = id % 768;
        const int r = id / 768;
        const int s = r % (TILES + 1);
        const int bb = r / (TILES + 1);
        const int p  = s * SPAN + q;
        const int oi = p - PADT;
        if ((unsigned)oi < (unsigned)OPB) out[(size_t)bb * OPB + oi] = 0.f;
    }
}

// One block = 16 frames = 4096-sample span. Reg staging + per-thread trick
// twiddle -> f16 Z in LDS -> 3 radix-8 stages (4 bflies/thread) ->
// register OLA -> direct stores pre-divided by interior envelope 1.5.
__global__ __launch_bounds__(256, 4) void istft16(
    const float* __restrict__ sr, const float* __restrict__ si,
    float* __restrict__ out)
{
    __shared__ __half2 stile[FR * FSTRIDE];  // 34880 B
    __shared__ float2  ph[257];              //  2056 B -> 36936 B, 4 blocks/CU

    const int tid = threadIdx.x;
    const int bid = blockIdx.x;
    const int nwg = NB * TILES;                           // 4096
    const int swz = (bid & 7) * (nwg >> 3) + (bid >> 3);  // XCD-chunked
    const int b    = swz / TILES;
    const int tile = swz % TILES;
    const int j0   = tile * FR;

    // ---- staging loads first (latency overlaps ph-table trig) ----
    const size_t gbase = (size_t)b * NBINS * TFR + (size_t)j0;
    const size_t gaA = gbase + (size_t)tid * TFR;
    const size_t gaB = gbase + (size_t)(512 - tid) * TFR;
    float4 rA0 = *(const float4*)(sr + gaA);
    float4 rA1 = *(const float4*)(sr + gaA + 4);
    float4 rA2 = *(const float4*)(sr + gaA + 8);
    float4 rA3 = *(const float4*)(sr + gaA + 12);
    float4 iA0 = *(const float4*)(si + gaA);
    float4 iA1 = *(const float4*)(si + gaA + 4);
    float4 iA2 = *(const float4*)(si + gaA + 8);
    float4 iA3 = *(const float4*)(si + gaA + 12);
    float4 rB0 = *(const float4*)(sr + gaB);
    float4 rB1 = *(const float4*)(sr + gaB + 4);
    float4 rB2 = *(const float4*)(sr + gaB + 8);
    float4 rB3 = *(const float4*)(sr + gaB + 12);
    float4 iB0 = *(const float4*)(si + gaB);
    float4 iB1 = *(const float4*)(si + gaB + 4);
    float4 iB2 = *(const float4*)(si + gaB + 8);
    float4 iB3 = *(const float4*)(si + gaB + 12);

    // bin-256 rows handled by lanes 0..7 (2 frames each) — off lane 0's chain
    float2 rc, ic;
    if (tid < 8) {
        const size_t gaC = gbase + (size_t)256 * TFR + 2*tid;
        rc = *(const float2*)(sr + gaC);
        ic = *(const float2*)(si + gaC);
    }
    if (tid == 0) {
        // irfft ignores Im of bins 0 and 512
        const float4 z4 = make_float4(0.f,0.f,0.f,0.f);
        iA0=iA1=iA2=iA3=z4; iB0=iB1=iB2=iB3=z4;
    }

    // ---- twiddle quarter-table (independent of loads) ----
    for (int m = tid; m < 257; m += 256) {
        float sv, cv;
        sincosf(TWOPI_1024 * (float)m, &sv, &cv);
        ph[m] = make_float2(cv, sv);
    }

    // ---- half-size trick in registers (per-thread sincos twiddle) ----
    {
        const float h = 0.5f * SSC;
        float swt, cwt;
        sincosf(TWOPI_1024 * (float)tid, &swt, &cwt);
        const int pk  = PIDX(tid);
        const int pk2 = PIDX(512 - tid);   // tid=0 -> slot 544 (unused)
#define TRICK(F, XKX, XKY, XMX, XMY) do {                                   \
            const float Ex = h*((XKX)+(XMX)), Ey = h*((XKY)-(XMY));         \
            const float Dx = h*((XKX)-(XMX)), Dy = h*((XKY)+(XMY));         \
            const float Ox = Dx*cwt - Dy*swt, Oy = Dx*swt + Dy*cwt;         \
            stile[(F)*FSTRIDE + pk]  = f2h(Ex - Oy, Ey + Ox);               \
            stile[(F)*FSTRIDE + pk2] = f2h(Ex + Oy, Ox - Ey);               \
        } while (0)
        TRICK(0,  rA0.x, iA0.x, rB0.x, iB0.x);
        TRICK(1,  rA0.y, iA0.y, rB0.y, iB0.y);
        TRICK(2,  rA0.z, iA0.z, rB0.z, iB0.z);
        TRICK(3,  rA0.w, iA0.w, rB0.w, iB0.w);
        TRICK(4,  rA1.x, iA1.x, rB1.x, iB1.x);
        TRICK(5,  rA1.y, iA1.y, rB1.y, iB1.y);
        TRICK(6,  rA1.z, iA1.z, rB1.z, iB1.z);
        TRICK(7,  rA1.w, iA1.w, rB1.w, iB1.w);
        TRICK(8,  rA2.x, iA2.x, rB2.x, iB2.x);
        TRICK(9,  rA2.y, iA2.y, rB2.y, iB2.y);
        TRICK(10, rA2.z, iA2.z, rB2.z, iB2.z);
        TRICK(11, rA2.w, iA2.w, rB2.w, iB2.w);
        TRICK(12, rA3.x, iA3.x, rB3.x, iB3.x);
        TRICK(13, rA3.y, iA3.y, rB3.y, iB3.y);
        TRICK(14, rA3.z, iA3.z, rB3.z, iB3.z);
        TRICK(15, rA3.w, iA3.w, rB3.w, iB3.w);
#undef TRICK
        if (tid < 8) {   // Z[256] = conj(X[256]) * SSC, 2 frames/lane
            stile[(2*tid)  *FSTRIDE + PIDX(256)] = f2h(rc.x * SSC, -ic.x * SSC);
            stile[(2*tid+1)*FSTRIDE + PIDX(256)] = f2h(rc.y * SSC, -ic.y * SSC);
        }
    }
    __syncthreads();                                   // B1

    // ---- 512-pt IFFT: 3 radix-8 stages, frame = tid>>4, 4 bflies/thread ----
    {
        const int f  = tid >> 4;
        __half2* row = &stile[f * FSTRIDE];
        const int i0 = tid & 15;
        fft_stage<64>(row, ph, i0);
        fft_stage<64>(row, ph, i0 + 16);
        fft_stage<64>(row, ph, i0 + 32);
        fft_stage<64>(row, ph, i0 + 48);
        __syncthreads();                               // B2
        fft_stage<8>(row, ph, i0);
        fft_stage<8>(row, ph, i0 + 16);
        fft_stage<8>(row, ph, i0 + 32);
        fft_stage<8>(row, ph, i0 + 48);
        __syncthreads();                               // B3
        fft_stage<1>(row, ph, i0);
        fft_stage<1>(row, ph, i0 + 16);
        fft_stage<1>(row, ph, i0 + 32);
        fft_stage<1>(row, ph, i0 + 48);
        __syncthreads();                               // B4
    }

    // ---- OLA into registers: cell c2 = f*128+n, owner c2&255 == tid ----
    const int nE = tid;
    const int nO = (tid + 128) & 255;
    const float2 wE0 = hann_pair(ph, nE);
    const float2 wE1 = hann_pair(ph, nE + 256);
    const float2 wO0 = hann_pair(ph, nO);
    const float2 wO1 = hann_pair(ph, nO + 256);

    float2 a0 = make_float2(0.f,0.f), a1=a0, a2=a0, a3=a0, a4=a0,
           a5 = a0, a6=a0, a7=a0, a8=a0, a9=a0;
    const bool tlo = (tid < 128);       // wave-coherent

#define OLA_STEP(F, KK, ACCV, W) do {                                       \
        const int n_ = (((F) & 1) ? nO : nE) + ((KK) << 8);                 \
        const int j_ = ((n_ & 7) << 6) | (n_ & 56) | (n_ >> 6);             \
        const float2 z_ = h2f(stile[(F)*FSTRIDE + PIDX(j_)]);               \
        ACCV.x += z_.x * W.x;                                               \
        ACCV.y += z_.y * W.y;                                               \
    } while (0)

    OLA_STEP(0,0,a0,wE0);  OLA_STEP(0,1,a1,wE1);
    if (tlo) { OLA_STEP(1,0,a1,wO0);  OLA_STEP(1,1,a2,wO1); }
    else     { OLA_STEP(1,0,a0,wO0);  OLA_STEP(1,1,a1,wO1); }
    OLA_STEP(2,0,a1,wE0);  OLA_STEP(2,1,a2,wE1);
    if (tlo) { OLA_STEP(3,0,a2,wO0);  OLA_STEP(3,1,a3,wO1); }
    else     { OLA_STEP(3,0,a1,wO0);  OLA_STEP(3,1,a2,wO1); }
    OLA_STEP(4,0,a2,wE0);  OLA_STEP(4,1,a3,wE1);
    if (tlo) { OLA_STEP(5,0,a3,wO0);  OLA_STEP(5,1,a4,wO1); }
    else     { OLA_STEP(5,0,a2,wO0);  OLA_STEP(5,1,a3,wO1); }
    OLA_STEP(6,0,a3,wE0);  OLA_STEP(6,1,a4,wE1);
    if (tlo) { OLA_STEP(7,0,a4,wO0);  OLA_STEP(7,1,a5,wO1); }
    else     { OLA_STEP(7,0,a3,wO0);  OLA_STEP(7,1,a4,wO1); }
    OLA_STEP(8,0,a4,wE0);  OLA_STEP(8,1,a5,wE1);
    if (tlo) { OLA_STEP(9,0,a5,wO0);  OLA_STEP(9,1,a6,wO1); }
    else     { OLA_STEP(9,0,a4,wO0);  OLA_STEP(9,1,a5,wO1); }
    OLA_STEP(10,0,a5,wE0); OLA_STEP(10,1,a6,wE1);
    if (tlo) { OLA_STEP(11,0,a6,wO0); OLA_STEP(11,1,a7,wO1); }
    else     { OLA_STEP(11,0,a5,wO0); OLA_STEP(11,1,a6,wO1); }
    OLA_STEP(12,0,a6,wE0); OLA_STEP(12,1,a7,wE1);
    if (tlo) { OLA_STEP(13,0,a7,wO0); OLA_STEP(13,1,a8,wO1); }
    else     { OLA_STEP(13,0,a6,wO0); OLA_STEP(13,1,a7,wO1); }
    OLA_STEP(14,0,a7,wE0); OLA_STEP(14,1,a8,wE1);
    if (tlo) { OLA_STEP(15,0,a8,wO0); OLA_STEP(15,1,a9,wO1); }
    else     { OLA_STEP(15,0,a7,wO0); OLA_STEP(15,1,a8,wO1); }
#undef OLA_STEP

    // ---- direct stores (values already env-divided by 1.5) ----
    const size_t ob = (size_t)b * OPB;
    const int pb = tile * SPAN;
#define STORE_SEAM(A, G) do {                                               \
        const int oi_ = pb + 2*(tid + 256*(G)) - PADT;                      \
        if ((unsigned)oi_ < (unsigned)OPB)       atomicAdd(&out[ob + oi_],     A.x); \
        if ((unsigned)(oi_+1) < (unsigned)OPB)   atomicAdd(&out[ob + oi_ + 1], A.y); \
    } while (0)
#define STORE_PLAIN(A, G) do {                                              \
        const int oi_ = pb + 2*(tid + 256*(G)) - PADT;                      \
        *(float2*)(out + ob + oi_) = A;                                     \
    } while (0)

    STORE_SEAM(a0, 0);                   // idx [0,512): head seam
    if (tlo) STORE_SEAM(a1, 1);          // [512,768): head seam
    else     STORE_PLAIN(a1, 1);         // [768,1024): interior
    STORE_PLAIN(a2, 2);
    STORE_PLAIN(a3, 3);
    STORE_PLAIN(a4, 4);
    STORE_PLAIN(a5, 5);
    STORE_PLAIN(a6, 6);
    STORE_PLAIN(a7, 7);                  // up to idx 4096
    STORE_SEAM(a8, 8);                   // [4096,4608): tail seam
    if (tlo) STORE_SEAM(a9, 9);          // [4608,4864): tail seam
#undef STORE_SEAM
#undef STORE_PLAIN
}

// env != 1.5 only within 384 samples of the global edges; rescale those.
__global__ __launch_bounds__(256) void edge_fix(float* __restrict__ out)
{
    const int id = blockIdx.x * 256 + threadIdx.x;   // 768 * NB total
    if (id >= 768 * NB) return;
    const int bb = id / 768;
    const int r  = id % 768;
    const int oi = (r < 384) ? r : (OPB - 768 + r);
    const int p  = oi + PADT;
    int jlo = (p - 768) >> 8; if (jlo < 0) jlo = 0;
    int jhi = p >> 8;         if (jhi > TFR - 1) jhi = TFR - 1;
    float e = 0.f;
    for (int j = jlo; j <= jhi; ++j) {
        const float wv = 0.5f - 0.5f * cosf(TWOPI_1024 * (float)(p - j * HOP));
        e += wv * wv;
    }
    out[(size_t)bb * OPB + oi] *= 1.5f / e;
}

extern "C" void kernel_launch(void* const* d_in, const int* in_sizes, int n_in,
                              void* d_out, int out_size, void* d_ws, size_t ws_size,
                              hipStream_t stream) {
    const float* sr = (const float*)d_in[0];
    const float* si = (const float*)d_in[1];
    float* out = (float*)d_out;

    hipLaunchKernelGGL(zero_seams, dim3(2048), dim3(256), 0, stream, out);
    hipLaunchKernelGGL(istft16, dim3(NB * TILES), dim3(256), 0, stream, sr, si, out);
    hipLaunchKernelGGL(edge_fix, dim3((768 * NB + 255) / 256), dim3(256), 0, stream, out);
}